// Round 3
// baseline (225.930 us; speedup 1.0000x reference)
//
#include <hip/hip_runtime.h>
#include <math.h>

#define N_PRED  12
#define N_DRIFT 2
#define N_DW    3
#define N_NODES 4096
#define BB      128
#define LL      16
#define BN      (BB * N_NODES)   // 524288 pairs
#define TPB     256
#define G       4                // pairs per thread
#define PPB     (TPB * G)        // 1024 pairs per block
#define NBLK    (BN / PPB)       // 512 blocks

// ---------------------------------------------------------------------------
// Pre-kernel: fold (deform ∘ conv_t) and (deform ∘ conv_n) into ONE uniform
// matrix M[48][24]  (cols 0..11 = Mt, cols 12..23 = Mn), interleaved so the
// main kernel's s_loads are contiguous 96-byte runs per kl.
// ---------------------------------------------------------------------------
__global__ void deform_precompute(const float* __restrict__ offset_t,
                                  const float* __restrict__ offset_n,
                                  const float* __restrict__ conv_t_w,
                                  const float* __restrict__ conv_n_w,
                                  float* __restrict__ M) {
    int t = threadIdx.x;
    if (t >= N_PRED * N_DW * LL) return;      // 576
    int q  = t % N_PRED;
    int kl = t / N_PRED;
    int k  = kl / LL;
    int l  = kl % LL;

    auto coef = [&](const float* off, int c) -> float {
        float pos = tanhf(off[k * N_PRED + c]) * (float)N_DRIFT
                    + (float)(c + N_DRIFT);
        float idf = floorf(pos);
        float fr  = pos - idf;
        int   id  = (int)idf;
        if (l == id)     return 1.0f - fr;
        if (l == id + 1) return fr;
        return 0.0f;
    };

    float mt = 0.0f;
    #pragma unroll
    for (int h = 0; h < 3; ++h) {
        int c = q - 1 + h;
        if (c < 0 || c >= N_PRED) continue;
        mt += conv_t_w[k * 3 + h] * coef(offset_t, c);
    }

    float mn = 0.0f;
    #pragma unroll
    for (int c = 0; c < N_PRED; ++c) {
        mn += conv_n_w[q * (N_PRED * N_DW) + c * N_DW + k] * coef(offset_n, c);
    }

    M[kl * 24 + q]      = mt;
    M[kl * 24 + 12 + q] = mn;
}

// ---------------------------------------------------------------------------
// Main kernel, R3: G=4 thread coarsening to amortize the uniform weight
// stream. Each s_loaded weight dword now feeds 4 FMAs (was 1) -> scalar
// stream pipelines under VALU instead of serializing it.
//  - no LDS (R2 proved coalescing wasn't the binder)
//  - K chunked 4x12 so x-chunk registers stay bounded; chunk loop rolled
//    to keep the body ~10 KB (I$-friendly)
//  - grid 512 blocks x 256 thr = 2 blocks/CU; launch_bounds(256,2) frees
//    the allocator up to 256 VGPRs for accs + prefetch
// ---------------------------------------------------------------------------
__global__ __launch_bounds__(TPB, 2) void deform_main(
        const float* __restrict__ inp,      // (BN, 3, 16)
        const float* __restrict__ ctrl,     // (BN, 12)
        const float* __restrict__ W,        // (12, 12)
        const float* __restrict__ bparam,   // (N_NODES, 12)
        const float* __restrict__ conv_t_b, // (1,)
        const float* __restrict__ conv_n_b, // (12,)
        const float* __restrict__ M,        // (48, 24) folded weights
        float* __restrict__ out) {          // (BN, 12)
    const int t    = threadIdx.x;
    const int base = blockIdx.x * PPB;

    int p[G];
    #pragma unroll
    for (int j = 0; j < G; ++j) p[j] = base + j * TPB + t;

    // ---- accumulators (biases) ----
    float acct[G][N_PRED], accn[G][N_PRED];
    {
        float ctb = conv_t_b[0];
        #pragma unroll
        for (int q = 0; q < N_PRED; ++q) {
            float cnb = conv_n_b[q];
            #pragma unroll
            for (int j = 0; j < G; ++j) {
                acct[j][q] = ctb;
                accn[j][q] = cnb;
            }
        }
    }

    // ---- main folded matvec, K chunked 4 x 12 ----
    #pragma unroll 1
    for (int c = 0; c < 4; ++c) {
        // load this chunk's x: 3 float4 per pair, 4 pairs
        float4 xc[G][3];
        #pragma unroll
        for (int j = 0; j < G; ++j) {
            const float4* xp = (const float4*)(inp + (size_t)p[j] * 48) + c * 3;
            #pragma unroll
            for (int i = 0; i < 3; ++i) xc[j][i] = xp[i];
        }
        const float* Mc = M + c * 12 * 24;
        #pragma unroll
        for (int kk = 0; kk < 12; ++kk) {
            float xv[G];
            #pragma unroll
            for (int j = 0; j < G; ++j)
                xv[j] = ((const float*)xc[j])[kk];
            #pragma unroll
            for (int q = 0; q < N_PRED; ++q) {
                float wt = Mc[kk * 24 + q];
                float wn = Mc[kk * 24 + 12 + q];
                #pragma unroll
                for (int j = 0; j < G; ++j) {
                    acct[j][q] = fmaf(wt, xv[j], acct[j][q]);
                    accn[j][q] = fmaf(wn, xv[j], accn[j][q]);
                }
            }
        }
    }

    // ---- gate + blend + store, one pair at a time (bounds register peak) ----
    #pragma unroll
    for (int j = 0; j < G; ++j) {
        const int n = p[j] & (N_NODES - 1);

        float cr[N_PRED];
        const float4* cp = (const float4*)(ctrl + (size_t)p[j] * N_PRED);
        #pragma unroll
        for (int i = 0; i < 3; ++i) {
            float4 v = cp[i];
            cr[4 * i + 0] = v.x; cr[4 * i + 1] = v.y;
            cr[4 * i + 2] = v.z; cr[4 * i + 3] = v.w;
        }

        float accg[N_PRED];
        const float4* bp = (const float4*)(bparam + (size_t)n * N_PRED);
        #pragma unroll
        for (int i = 0; i < 3; ++i) {
            float4 v = bp[i];
            accg[4 * i + 0] = v.x; accg[4 * i + 1] = v.y;
            accg[4 * i + 2] = v.z; accg[4 * i + 3] = v.w;
        }

        #pragma unroll
        for (int pp = 0; pp < N_PRED; ++pp) {
            float cv = cr[pp];
            #pragma unroll
            for (int q = 0; q < N_PRED; ++q) {
                accg[q] = fmaf(cv, W[pp * N_PRED + q], accg[q]);
            }
        }

        float4 o4[3];
        float* ov = (float*)o4;
        #pragma unroll
        for (int q = 0; q < N_PRED; ++q) {
            float g = 1.0f / (1.0f + __expf(-accg[q]));
            ov[q] = accn[j][q] * g + acct[j][q] * (1.0f - g);
        }
        float4* op = (float4*)(out + (size_t)p[j] * N_PRED);
        op[0] = o4[0]; op[1] = o4[1]; op[2] = o4[2];
    }
}

extern "C" void kernel_launch(void* const* d_in, const int* in_sizes, int n_in,
                              void* d_out, int out_size, void* d_ws, size_t ws_size,
                              hipStream_t stream) {
    const float* inp      = (const float*)d_in[0];
    const float* ctrl     = (const float*)d_in[1];
    const float* offset_t = (const float*)d_in[2];
    const float* offset_n = (const float*)d_in[3];
    const float* conv_t_w = (const float*)d_in[4];
    const float* conv_t_b = (const float*)d_in[5];
    const float* conv_n_w = (const float*)d_in[6];
    const float* conv_n_b = (const float*)d_in[7];
    const float* W        = (const float*)d_in[8];
    const float* bparam   = (const float*)d_in[9];
    float* out = (float*)d_out;

    float* M = (float*)d_ws;             // 48*24 floats = 4608 B

    deform_precompute<<<1, 576, 0, stream>>>(offset_t, offset_n,
                                             conv_t_w, conv_n_w, M);
    deform_main<<<NBLK, TPB, 0, stream>>>(inp, ctrl, W, bparam,
                                          conv_t_b, conv_n_b, M, out);
}

// Round 4
// 219.630 us; speedup vs baseline: 1.0287x; 1.0287x over previous
//
#include <hip/hip_runtime.h>
#include <math.h>

#define N_PRED  12
#define N_DRIFT 2
#define N_DW    3
#define N_NODES 4096
#define BB      128
#define BN      (BB * N_NODES)     // 524288 pairs
#define NTILES  (BN / 16)          // 32768 row-tiles of 16 pairs
#define RPW     4                  // row-tiles per wave
#define WPB     4                  // waves per block (256 thr)
#define NBLK    (NTILES / (RPW * WPB))   // 2048 blocks

typedef __attribute__((ext_vector_type(8))) short bf16x8;
typedef __attribute__((ext_vector_type(4))) float f32x4;

static __device__ __forceinline__ unsigned short bf16_rne(float f) {
    unsigned int u = __float_as_uint(f);
    u = (u + 0x7FFFu + ((u >> 16) & 1u)) >> 16;
    return (unsigned short)u;
}
static __device__ __forceinline__ float bf16_to_f32(unsigned short h) {
    return __uint_as_float(((unsigned int)h) << 16);
}

// ---------------------------------------------------------------------------
// Precompute: build the folded uniform matrix M[64][48] (z-dim x out-dim):
//   z = [ x(48) | ctrl(12) | 1 | 0 0 0 ]
//   cols 0-11:  pred_t (deform_t folded with conv_t);  row60 = conv_t_b
//   cols 16-27: pred_n (deform_n folded with conv_n);  row60 = conv_n_b
//   cols 32-43: gate linear W (rows 48-59 = ctrl)
// then emit it as bf16 hi/lo MFMA B-fragments (16x16x32: lane-> n=lane&15,
// k = (lane>>4)*8 + j) for 3 col-tiles x 2 K-halves. 12288 B into d_ws.
// ---------------------------------------------------------------------------
__global__ void deform_precompute(const float* __restrict__ offset_t,
                                  const float* __restrict__ offset_n,
                                  const float* __restrict__ conv_t_w,
                                  const float* __restrict__ conv_t_b,
                                  const float* __restrict__ conv_n_w,
                                  const float* __restrict__ conv_n_b,
                                  const float* __restrict__ W,
                                  unsigned short* __restrict__ wsB) {
    __shared__ float Ms[64][48];
    const int t = threadIdx.x;   // 256 threads

    auto coef = [&](const float* off, int kw, int c, int l) -> float {
        float pos = tanhf(off[kw * N_PRED + c]) * (float)N_DRIFT
                    + (float)(c + N_DRIFT);
        float idf = floorf(pos);
        float fr  = pos - idf;
        int   id  = (int)idf;
        if (l == id)     return 1.0f - fr;
        if (l == id + 1) return fr;
        return 0.0f;
    };

    for (int e = t; e < 64 * 48; e += 256) {
        int k = e / 48, col = e % 48;
        float v = 0.0f;
        if (k < 48) {
            int kw = k >> 4, l = k & 15;
            if (col < 12) {                       // Mt
                #pragma unroll
                for (int h = 0; h < 3; ++h) {
                    int c = col - 1 + h;
                    if (c < 0 || c >= N_PRED) continue;
                    v += conv_t_w[kw * 3 + h] * coef(offset_t, kw, c, l);
                }
            } else if (col >= 16 && col < 28) {   // Mn
                int q = col - 16;
                for (int c = 0; c < N_PRED; ++c)
                    v += conv_n_w[q * (N_PRED * N_DW) + c * N_DW + kw]
                         * coef(offset_n, kw, c, l);
            }
        } else if (k < 60) {                      // gate W rows
            if (col >= 32 && col < 44) v = W[(k - 48) * N_PRED + (col - 32)];
        } else if (k == 60) {                     // bias row (z = 1)
            if (col < 12)                 v = conv_t_b[0];
            else if (col >= 16 && col < 28) v = conv_n_b[col - 16];
        }
        Ms[k][col] = v;
    }
    __syncthreads();

    // emit fragments: 3 ct x 2 kh x 64 lanes x 8 j  (hi & lo per element)
    for (int e = t; e < 3 * 2 * 64 * 8; e += 256) {
        int j    = e & 7;
        int lane = (e >> 3) & 63;
        int kh   = (e >> 9) & 1;
        int ct   = e >> 10;
        int k    = kh * 32 + ((lane >> 4) << 3) + j;
        int col  = (lane & 15) + 16 * ct;
        float v  = Ms[k][col];
        unsigned short hi = bf16_rne(v);
        unsigned short lo = bf16_rne(v - bf16_to_f32(hi));
        int off_hi = ((ct * 2 + kh) * 2) * 512 + lane * 8 + j;
        wsB[off_hi]       = hi;
        wsB[off_hi + 512] = lo;
    }
}

// ---------------------------------------------------------------------------
// Main kernel, R4: MFMA. Weights are VGPR-resident B-fragments loaded ONCE
// per wave -> zero scalar-stream in the hot loop (the R1-R3 binder).
// Per 16-pair row-tile: build A hi/lo frags from global, 18 MFMAs
// (3 col-tiles x 2 K-halves x {AhBh, AhBl, AlBh}), epilogue gate+blend.
// C layout (verified): col = lane&15, row = (lane>>4)*4 + reg.
// ---------------------------------------------------------------------------
__global__ __launch_bounds__(256) void deform_main(
        const float* __restrict__ inp,      // (BN, 48)
        const float* __restrict__ ctrl,     // (BN, 12)
        const float* __restrict__ bparam,   // (N_NODES, 12)
        const unsigned short* __restrict__ wsB,
        float* __restrict__ out) {          // (BN, 12)
    const int lane = threadIdx.x & 63;
    const int wid  = blockIdx.x * WPB + (threadIdx.x >> 6);
    const int quad = lane >> 4;
    const int col  = lane & 15;

    // ---- load B fragments (loop-invariant, 12 x 16B per lane) ----
    bf16x8 Bh[3][2], Bl[3][2];
    #pragma unroll
    for (int ct = 0; ct < 3; ++ct) {
        #pragma unroll
        for (int kh = 0; kh < 2; ++kh) {
            const bf16x8* ph =
                (const bf16x8*)(wsB + ((ct * 2 + kh) * 2) * 512);
            Bh[ct][kh] = ph[lane];
            Bl[ct][kh] = ph[lane + 64];   // +512 ushorts = +64 frags
        }
    }

    const bool active = (col < 12);
    const int  bcol   = active ? col : 11;

    #pragma unroll 1
    for (int r = 0; r < RPW; ++r) {
        const int rt        = wid * RPW + r;
        const int base_pair = rt * 16;
        const int pair      = base_pair + col;

        // ---- gather z[64] pieces for this lane (k = kh*32 + quad*8 + j) ----
        const float4* xp =
            (const float4*)(inp + (size_t)pair * 48 + quad * 8);
        float4 a0 = xp[0], a1 = xp[1];                 // half0: k 0..31

        const float* bbase;
        if (quad < 2)      bbase = inp  + (size_t)pair * 48 + 32 + quad * 8;
        else if (quad == 2) bbase = ctrl + (size_t)pair * 12;
        else               bbase = ctrl + (size_t)pair * 12 + 8;
        float4 b0 = *(const float4*)bbase;             // half1 first 4
        float4 b1;
        if (quad == 3) b1 = make_float4(1.0f, 0.0f, 0.0f, 0.0f);
        else           b1 = *((const float4*)bbase + 1);

        // ---- split into bf16 hi/lo A-fragments ----
        float za[8] = {a0.x, a0.y, a0.z, a0.w, a1.x, a1.y, a1.z, a1.w};
        float zb[8] = {b0.x, b0.y, b0.z, b0.w, b1.x, b1.y, b1.z, b1.w};
        union { bf16x8 v; unsigned short u[8]; } Ah0, Al0, Ah1, Al1;
        #pragma unroll
        for (int j = 0; j < 8; ++j) {
            unsigned short h0 = bf16_rne(za[j]);
            Ah0.u[j] = h0;
            Al0.u[j] = bf16_rne(za[j] - bf16_to_f32(h0));
            unsigned short h1 = bf16_rne(zb[j]);
            Ah1.u[j] = h1;
            Al1.u[j] = bf16_rne(zb[j] - bf16_to_f32(h1));
        }

        // ---- 18 MFMAs: per col-tile, AhBh + AhBl + AlBh over 2 K-halves ----
        f32x4 C0 = {0.f, 0.f, 0.f, 0.f}, C1 = C0, C2 = C0;
        C0 = __builtin_amdgcn_mfma_f32_16x16x32_bf16(Ah0.v, Bh[0][0], C0, 0, 0, 0);
        C0 = __builtin_amdgcn_mfma_f32_16x16x32_bf16(Ah1.v, Bh[0][1], C0, 0, 0, 0);
        C0 = __builtin_amdgcn_mfma_f32_16x16x32_bf16(Ah0.v, Bl[0][0], C0, 0, 0, 0);
        C0 = __builtin_amdgcn_mfma_f32_16x16x32_bf16(Ah1.v, Bl[0][1], C0, 0, 0, 0);
        C0 = __builtin_amdgcn_mfma_f32_16x16x32_bf16(Al0.v, Bh[0][0], C0, 0, 0, 0);
        C0 = __builtin_amdgcn_mfma_f32_16x16x32_bf16(Al1.v, Bh[0][1], C0, 0, 0, 0);

        C1 = __builtin_amdgcn_mfma_f32_16x16x32_bf16(Ah0.v, Bh[1][0], C1, 0, 0, 0);
        C1 = __builtin_amdgcn_mfma_f32_16x16x32_bf16(Ah1.v, Bh[1][1], C1, 0, 0, 0);
        C1 = __builtin_amdgcn_mfma_f32_16x16x32_bf16(Ah0.v, Bl[1][0], C1, 0, 0, 0);
        C1 = __builtin_amdgcn_mfma_f32_16x16x32_bf16(Ah1.v, Bl[1][1], C1, 0, 0, 0);
        C1 = __builtin_amdgcn_mfma_f32_16x16x32_bf16(Al0.v, Bh[1][0], C1, 0, 0, 0);
        C1 = __builtin_amdgcn_mfma_f32_16x16x32_bf16(Al1.v, Bh[1][1], C1, 0, 0, 0);

        C2 = __builtin_amdgcn_mfma_f32_16x16x32_bf16(Ah0.v, Bh[2][0], C2, 0, 0, 0);
        C2 = __builtin_amdgcn_mfma_f32_16x16x32_bf16(Ah1.v, Bh[2][1], C2, 0, 0, 0);
        C2 = __builtin_amdgcn_mfma_f32_16x16x32_bf16(Ah0.v, Bl[2][0], C2, 0, 0, 0);
        C2 = __builtin_amdgcn_mfma_f32_16x16x32_bf16(Ah1.v, Bl[2][1], C2, 0, 0, 0);
        C2 = __builtin_amdgcn_mfma_f32_16x16x32_bf16(Al0.v, Bh[2][0], C2, 0, 0, 0);
        C2 = __builtin_amdgcn_mfma_f32_16x16x32_bf16(Al1.v, Bh[2][1], C2, 0, 0, 0);

        // ---- epilogue: gate + blend + store ----
        // C element i -> pair row (quad*4 + i), output feature = col
        #pragma unroll
        for (int i = 0; i < 4; ++i) {
            int prow = base_pair + quad * 4 + i;
            int n    = prow & (N_NODES - 1);
            float bp = bparam[n * N_PRED + bcol];
            float g  = 1.0f / (1.0f + __expf(-(C2[i] + bp)));
            float o  = C1[i] * g + C0[i] * (1.0f - g);
            if (active) out[(size_t)prow * N_PRED + col] = o;
        }
    }
}

extern "C" void kernel_launch(void* const* d_in, const int* in_sizes, int n_in,
                              void* d_out, int out_size, void* d_ws, size_t ws_size,
                              hipStream_t stream) {
    const float* inp      = (const float*)d_in[0];
    const float* ctrl     = (const float*)d_in[1];
    const float* offset_t = (const float*)d_in[2];
    const float* offset_n = (const float*)d_in[3];
    const float* conv_t_w = (const float*)d_in[4];
    const float* conv_t_b = (const float*)d_in[5];
    const float* conv_n_w = (const float*)d_in[6];
    const float* conv_n_b = (const float*)d_in[7];
    const float* W        = (const float*)d_in[8];
    const float* bparam   = (const float*)d_in[9];
    float* out = (float*)d_out;

    unsigned short* wsB = (unsigned short*)d_ws;   // 12288 B of fragments

    deform_precompute<<<1, 256, 0, stream>>>(offset_t, offset_n,
                                             conv_t_w, conv_t_b,
                                             conv_n_w, conv_n_b, W, wsB);
    deform_main<<<NBLK, 256, 0, stream>>>(inp, ctrl, bparam, wsB, out);
}